// Round 7
// baseline (451.725 us; speedup 1.0000x reference)
//
#include <hip/hip_runtime.h>
#include <hip/hip_bf16.h>
#include <float.h>
#include <math.h>

// Problem constants (B, L, H, D fixed by the reference setup)
constexpr int B = 4;
constexpr int L = 2048;
constexpr int H = 16;
constexpr int D = 64;
constexpr int U = 40;   // u_top = min(5*ceil(ln(2048)), 2048) = 40
constexpr int UG = 8;   // u's per pv block
constexpr int NCH = 8;  // L-chunks per (b,h) in scores kernel
constexpr int RCH = 8;  // row chunks (256 rows each) in pv_partial
constexpr int NE = 8;   // eighths of the key range (256 rows each)

typedef float floatx4 __attribute__((ext_vector_type(4)));

__device__ inline float dot8(floatx4 a0, floatx4 a1, floatx4 b0, floatx4 b1) {
    return a0.x * b0.x + a0.y * b0.y + a0.z * b0.z + a0.w * b0.w
         + a1.x * b1.x + a1.y * b1.y + a1.z * b1.z + a1.w * b1.w;
}

// ---------------------------------------------------------------------------
// Kernel A: partition each l's samples by key-eighth (deterministic, s-order).
// cnt[e*L + l], part[(e*L + l)*SKC + c] = global kidx. Shared by all (b,h).
// ---------------------------------------------------------------------------
template<int SKC>
__global__ void partition_kernel(const int* __restrict__ sidx, int* __restrict__ cnt,
                                 int* __restrict__ part) {
    int l = blockIdx.x * 256 + threadIdx.x;
    if (l >= L) return;
    int idxs[SKC];
    #pragma unroll
    for (int s = 0; s < SKC; ++s) idxs[s] = sidx[l * SKC + s];
    #pragma unroll
    for (int e = 0; e < NE; ++e) {
        int c = 0;
        #pragma unroll
        for (int s = 0; s < SKC; ++s) {
            if ((idxs[s] >> 8) == e) { part[((size_t)e * L + l) * SKC + c] = idxs[s]; ++c; }
        }
        cnt[e * L + l] = c;
    }
}

// ---------------------------------------------------------------------------
// Kernel B: M partials with k staged in LDS. Block = (bh XCD-affine, eighth).
// 512 threads (8 waves); wave handles l = w, w+8, ... Lane = g8*8+dpart:
// group g8 = one sample, dpart = 8-elem slice of D. 1-deep prefetch of
// (q row, cnt, first 8 entries). Bank-optimal LDS reads (8 rows x 128B).
// ---------------------------------------------------------------------------
template<int SKC>
__global__ void m_lds_kernel(const float* __restrict__ q, const float* __restrict__ k,
                             const int* __restrict__ cnt, const int* __restrict__ part,
                             float* __restrict__ pM, float* __restrict__ pS) {
    int blk = blockIdx.x;
    int xcd = blk & 7;
    int bh = ((blk >> 3) & 7) * 8 + xcd;   // bh%8 == blk%8 (XCD affinity; 8 eighths of a bh share an XCD)
    int e = blk >> 6;                       // 0..7
    int b = bh >> 4, h = bh & 15;
    int t = threadIdx.x;

    __shared__ __align__(16) float lk[256 * 64];

    // stage 256 k rows (e*256 .. e*256+255) of (b,h): 64 KB, coalesced
    {
        const floatx4* ksrc = reinterpret_cast<const floatx4*>(
            k + ((size_t)(b * L + (e << 8)) * H + h) * D);
        floatx4* ldst = reinterpret_cast<floatx4*>(lk);
        for (int j = t; j < 256 * 16; j += 512) {
            int r = j >> 4, cc = j & 15;
            ldst[r * 16 + cc] = ksrc[(size_t)r * (H * D / 4) + cc];
        }
    }
    __syncthreads();

    int w = t >> 6;
    int lane = t & 63;
    int g8 = lane >> 3;
    int dpart = lane & 7;

    // prefetch state for first l
    int l = w;
    int n_cur = cnt[e * L + l];
    const float* qr = q + ((size_t)(b * L + l) * H + h) * D;
    floatx4 q0_cur = *reinterpret_cast<const floatx4*>(qr + dpart * 4);
    floatx4 q1_cur = *reinterpret_cast<const floatx4*>(qr + 32 + dpart * 4);
    int pf = n_cur > 0 ? min(g8, n_cur - 1) : 0;
    int ent_cur = part[((size_t)e * L + l) * SKC + pf];

    while (l < L) {
        int ln = l + 8;
        int n_nxt = 0, ent_nxt = 0;
        floatx4 q0_nxt, q1_nxt;
        if (ln < L) {
            n_nxt = cnt[e * L + ln];
            const float* qn = q + ((size_t)(b * L + ln) * H + h) * D;
            q0_nxt = *reinterpret_cast<const floatx4*>(qn + dpart * 4);
            q1_nxt = *reinterpret_cast<const floatx4*>(qn + 32 + dpart * 4);
            int pfn = n_nxt > 0 ? min(g8, n_nxt - 1) : 0;
            ent_nxt = part[((size_t)e * L + ln) * SKC + pfn];
        }

        float mx = -FLT_MAX, sm = 0.f;
        for (int c = 0; c < n_cur; c += 8) {
            int s = c + g8;
            bool valid = s < n_cur;
            int kidx;
            if (c == 0) kidx = ent_cur;
            else kidx = part[((size_t)e * L + l) * SKC + (valid ? s : n_cur - 1)];
            int row = kidx - (e << 8);     // 0..255
            int off = row * 64 + dpart * 4;
            floatx4 ka = *reinterpret_cast<const floatx4*>(&lk[off]);
            floatx4 kb = *reinterpret_cast<const floatx4*>(&lk[off + 32]);
            float p = dot8(q0_cur, q1_cur, ka, kb);
            p += __shfl_xor(p, 1);
            p += __shfl_xor(p, 2);
            p += __shfl_xor(p, 4);
            if (valid) { mx = fmaxf(mx, p); sm += p; }
        }
        #pragma unroll
        for (int off = 8; off <= 32; off <<= 1) {
            mx = fmaxf(mx, __shfl_xor(mx, off));
            sm += __shfl_xor(sm, off);
        }
        if (lane == 0) {
            pM[((size_t)e * 64 + bh) * L + l] = mx;
            pS[((size_t)e * 64 + bh) * L + l] = sm;
        }

        l = ln; n_cur = n_nxt; q0_cur = q0_nxt; q1_cur = q1_nxt; ent_cur = ent_nxt;
    }
}

// ---------------------------------------------------------------------------
// Kernel C: combine partials -> M, fused with the v->out HBM copy.
// Blocks [0,512): combine 64*2048 outputs; ALL 2048 blocks: grid-stride copy.
// ---------------------------------------------------------------------------
__global__ void combine_copy_kernel(const float* __restrict__ pM, const float* __restrict__ pS,
                                    float* __restrict__ M, const float* __restrict__ v,
                                    float* __restrict__ out, int n4) {
    int blk = blockIdx.x;
    int t = threadIdx.x;
    int tid = blk * 256 + t;

    if (blk < 512) {
        // combine: tid = bh*L + l
        float mx = -FLT_MAX, sm = 0.f;
        #pragma unroll
        for (int e = 0; e < NE; ++e) {
            mx = fmaxf(mx, pM[(size_t)e * 64 * L + tid]);
            sm += pS[(size_t)e * 64 * L + tid];
        }
        M[tid] = mx - sm * (1.0f / (float)L);
    }

    const floatx4* src = reinterpret_cast<const floatx4*>(v);
    floatx4* dst = reinterpret_cast<floatx4*>(out);
    for (int i = tid; i < n4; i += 2048 * 256) {
        floatx4 x = __builtin_nontemporal_load(src + i);
        __builtin_nontemporal_store(x, dst + i);
    }
}

// Standalone copy (fallback path)
__global__ void copy_v_kernel(const float* __restrict__ v, float* __restrict__ out, int n4) {
    int i = blockIdx.x * blockDim.x + threadIdx.x;
    int stride = gridDim.x * blockDim.x;
    const floatx4* src = reinterpret_cast<const floatx4*>(v);
    floatx4* dst = reinterpret_cast<floatx4*>(out);
    for (; i < n4; i += stride) {
        floatx4 x = __builtin_nontemporal_load(src + i);
        __builtin_nontemporal_store(x, dst + i);
    }
}

// Fallback M for unexpected SK
__global__ void compute_M_kernel(const float* __restrict__ q, const float* __restrict__ k,
                                 const int* __restrict__ sidx, float* __restrict__ M, int SK) {
    int bl = blockIdx.x;
    int b = bl / L;
    int l = bl % L;
    int t = threadIdx.x;
    int h = t >> 4;
    int dg = t & 15;

    const float* qrow = q + ((size_t)(b * L + l)) * H * D + h * D + dg * 4;
    float4 qv = *reinterpret_cast<const float4*>(qrow);

    float mx = -FLT_MAX;
    float sm = 0.f;
    for (int s = 0; s < SK; ++s) {
        int kidx = sidx[l * SK + s];
        const float* krow = k + ((size_t)(b * L + kidx)) * H * D + h * D + dg * 4;
        float4 kv = *reinterpret_cast<const float4*>(krow);
        float p = qv.x * kv.x + qv.y * kv.y + qv.z * kv.z + qv.w * kv.w;
        #pragma unroll
        for (int off = 8; off >= 1; off >>= 1) p += __shfl_xor(p, off, 16);
        mx = fmaxf(mx, p);
        sm += p;
    }
    if (dg == 0) {
        M[((size_t)(b * H + h)) * L + l] = mx - sm * (1.0f / (float)L);
    }
}

// ---------------------------------------------------------------------------
// Top-k: one wave per (b,h), register-resident, jax.lax.top_k tie-breaking.
// ---------------------------------------------------------------------------
__global__ void topk_wave_kernel(const float* __restrict__ M, int* __restrict__ Mtop) {
    int bh = blockIdx.x;
    int lane = threadIdx.x;  // 0..63
    const float* m = M + (size_t)bh * L;

    float v[32];
    #pragma unroll
    for (int j = 0; j < 32; ++j) v[j] = m[j * 64 + lane];

    for (int u = 0; u < U; ++u) {
        float bv = -FLT_MAX;
        int bi = 0x7fffffff;
        #pragma unroll
        for (int j = 0; j < 32; ++j) {
            int idx = j * 64 + lane;
            bool take = (v[j] > bv) || (v[j] == bv && idx < bi);
            bv = take ? v[j] : bv;
            bi = take ? idx : bi;
        }
        #pragma unroll
        for (int off = 1; off < 64; off <<= 1) {
            float ov = __shfl_xor(bv, off);
            int   oi = __shfl_xor(bi, off);
            bool take = (ov > bv) || (ov == bv && oi < bi);
            bv = take ? ov : bv;
            bi = take ? oi : bi;
        }
        if (lane == 0) Mtop[bh * U + u] = bi;
        #pragma unroll
        for (int j = 0; j < 32; ++j) {
            if (bi == j * 64 + lane) v[j] = -FLT_MAX;
        }
    }
}

// ---------------------------------------------------------------------------
// Scores. Block = (bh, L-chunk of 256). One thread per key row.
// ---------------------------------------------------------------------------
__global__ void scores_kernel(const float* __restrict__ q, const float* __restrict__ k,
                              const int* __restrict__ Mtop, float* __restrict__ sc) {
    int blk = blockIdx.x;
    int bh = blk >> 3;           // /NCH
    int ch = blk & (NCH - 1);
    int b = bh / H, h = bh % H;
    int t = threadIdx.x;

    __shared__ __align__(16) float qs[U][D];
    for (int i = t; i < U * D; i += 256) {
        int u = i >> 6, dd = i & 63;
        int qi = Mtop[bh * U + u];
        qs[u][dd] = q[((size_t)(b * L + qi)) * H * D + h * D + dd];
    }
    __syncthreads();

    int r = ch * 256 + t;
    const float4* krow = reinterpret_cast<const float4*>(k + ((size_t)(b * L + r)) * H * D + h * D);
    float4 kr[16];
    #pragma unroll
    for (int j = 0; j < 16; ++j) kr[j] = krow[j];

    float* scb = sc + (size_t)bh * U * L;
    for (int u = 0; u < U; ++u) {
        const float4* qrow = reinterpret_cast<const float4*>(qs[u]);
        float acc = 0.f;
        #pragma unroll
        for (int j = 0; j < 16; ++j) {
            float4 qv = qrow[j];
            acc += qv.x * kr[j].x + qv.y * kr[j].y + qv.z * kr[j].z + qv.w * kr[j].w;
        }
        scb[(size_t)u * L + r] = acc * 0.125f;
    }
}

// ---------------------------------------------------------------------------
// Softmax over each sc row of L. Block per (bh,u). 8 vals/thread.
// ---------------------------------------------------------------------------
__global__ void softmax_kernel(float* __restrict__ sc) {
    int bhu = blockIdx.x;
    float* s = sc + (size_t)bhu * L;
    int t = threadIdx.x;
    __shared__ float redm[4];
    __shared__ float reds[4];

    float4 a = reinterpret_cast<const float4*>(s)[t];
    float4 c = reinterpret_cast<const float4*>(s)[t + 256];

    float m = fmaxf(fmaxf(fmaxf(a.x, a.y), fmaxf(a.z, a.w)),
                    fmaxf(fmaxf(c.x, c.y), fmaxf(c.z, c.w)));
    #pragma unroll
    for (int off = 32; off >= 1; off >>= 1) m = fmaxf(m, __shfl_xor(m, off));
    if ((t & 63) == 0) redm[t >> 6] = m;
    __syncthreads();
    float gm = fmaxf(fmaxf(redm[0], redm[1]), fmaxf(redm[2], redm[3]));

    a.x = __expf(a.x - gm); a.y = __expf(a.y - gm);
    a.z = __expf(a.z - gm); a.w = __expf(a.w - gm);
    c.x = __expf(c.x - gm); c.y = __expf(c.y - gm);
    c.z = __expf(c.z - gm); c.w = __expf(c.w - gm);
    float ls = a.x + a.y + a.z + a.w + c.x + c.y + c.z + c.w;
    #pragma unroll
    for (int off = 32; off >= 1; off >>= 1) ls += __shfl_xor(ls, off);
    if ((t & 63) == 0) reds[t >> 6] = ls;
    __syncthreads();
    float inv = 1.0f / (reds[0] + reds[1] + reds[2] + reds[3]);

    a.x *= inv; a.y *= inv; a.z *= inv; a.w *= inv;
    c.x *= inv; c.y *= inv; c.z *= inv; c.w *= inv;
    reinterpret_cast<float4*>(s)[t] = a;
    reinterpret_cast<float4*>(s)[t + 256] = c;
}

// ---------------------------------------------------------------------------
// PV stage 1: partial PV. Block = (bh, ug, rch) = 2560 blocks.
// ---------------------------------------------------------------------------
__global__ void pv_partial_kernel(const float* __restrict__ v, const float* __restrict__ p,
                                  float* __restrict__ partial) {
    int blk = blockIdx.x;
    int xcd = blk & 7;
    int rest = blk >> 3;          // 0..319
    int bh_hi = rest & 7;
    int rest2 = rest >> 3;        // 0..39
    int bh = bh_hi * 8 + xcd;
    int ug = rest2 >> 3;          // /RCH, 0..4
    int rch = rest2 & (RCH - 1);  // 0..7
    int b = bh / H, h = bh % H;
    int t = threadIdx.x;
    int d = t & 63;
    int w = t >> 6;

    const float* pb = p + ((size_t)bh * U + (size_t)ug * UG) * L;
    const float* vb = v + ((size_t)b * L * H + h) * D + d;

    float acc[UG];
    #pragma unroll
    for (int u = 0; u < UG; ++u) acc[u] = 0.f;

    int r0 = rch * 256 + w * 64;
    for (int rr = 0; rr < 64; rr += 2) {
        int r1 = r0 + rr;
        int r2 = r0 + rr + 1;
        float v1 = vb[(size_t)r1 * H * D];
        float v2 = vb[(size_t)r2 * H * D];
        #pragma unroll
        for (int u = 0; u < UG; ++u) {
            float p1 = pb[(size_t)u * L + r1];
            float p2 = pb[(size_t)u * L + r2];
            acc[u] = fmaf(p2, v2, fmaf(p1, v1, acc[u]));
        }
    }

    __shared__ float red[4][UG][64];
    #pragma unroll
    for (int u = 0; u < UG; ++u) red[w][u][d] = acc[u];
    __syncthreads();

    for (int i = t; i < UG * 64; i += 256) {
        int u = i >> 6, dd = i & 63;
        float s = red[0][u][dd] + red[1][u][dd] + red[2][u][dd] + red[3][u][dd];
        partial[(((size_t)bh * U + ug * UG + u) * RCH + rch) * 64 + dd] = s;
    }
}

// ---------------------------------------------------------------------------
// PV stage 2: reduce partials and scatter into out.
// ---------------------------------------------------------------------------
__global__ void pv_reduce_kernel(const float* __restrict__ partial, const int* __restrict__ Mtop,
                                 float* __restrict__ out) {
    int idx = blockIdx.x * 256 + threadIdx.x;   // 0 .. B*H*U*64-1
    int dd = idx & 63;
    int bhu = idx >> 6;                          // 0..2559
    int bh = bhu / U;
    int b = bh / H, h = bh % H;

    const float* pp = partial + (size_t)bhu * RCH * 64 + dd;
    float s = 0.f;
    #pragma unroll
    for (int c = 0; c < RCH; ++c) s += pp[c * 64];

    int qi = Mtop[bhu];
    out[((size_t)(b * L + qi) * H + h) * D + dd] = s;
}

// ---------------------------------------------------------------------------
// Single-stage PV (fallback if partial buffer doesn't fit).
// ---------------------------------------------------------------------------
__global__ void pv_kernel(const float* __restrict__ v, const float* __restrict__ p,
                          const int* __restrict__ Mtop, float* __restrict__ out) {
    int blk = blockIdx.x;
    int xcd = blk & 7;
    int rest = blk >> 3;
    int bh_hi = rest & 7;
    int ug = rest >> 3;
    int bh = bh_hi * 8 + xcd;
    int b = bh / H, h = bh % H;
    int t = threadIdx.x;
    int d = t & 63;
    int w = t >> 6;

    const float* pb = p + ((size_t)bh * U + (size_t)ug * UG) * L;
    float acc[UG];
    #pragma unroll
    for (int u = 0; u < UG; ++u) acc[u] = 0.f;

    for (int r = w * 512; r < (w + 1) * 512; ++r) {
        float vv = v[((size_t)(b * L + r)) * H * D + h * D + d];
        #pragma unroll
        for (int u = 0; u < UG; ++u) acc[u] += pb[(size_t)u * L + r] * vv;
    }

    __shared__ float red[4][UG][64];
    #pragma unroll
    for (int u = 0; u < UG; ++u) red[w][u][d] = acc[u];
    __syncthreads();

    for (int i = t; i < UG * 64; i += 256) {
        int u = i >> 6, dd = i & 63;
        float s = red[0][u][dd] + red[1][u][dd] + red[2][u][dd] + red[3][u][dd];
        int qi = Mtop[bh * U + ug * UG + u];
        out[((size_t)(b * L + qi)) * H * D + h * D + dd] = s;
    }
}

// ---------------------------------------------------------------------------
// Fallback attention if workspace too small for the score buffer.
// ---------------------------------------------------------------------------
__global__ void attn_kernel_fallback(const float* __restrict__ q, const float* __restrict__ k,
                                     const float* __restrict__ v, const int* __restrict__ Mtop,
                                     float* __restrict__ out) {
    int blk = blockIdx.x;
    int bh = blk / U;
    int u = blk % U;
    int b = bh / H;
    int h = bh % H;
    int qi = Mtop[bh * U + u];

    __shared__ float sc[L];
    __shared__ float qs[D];
    __shared__ float red[4];
    __shared__ float ctx_s[4][D];

    int t = threadIdx.x;
    if (t < D) qs[t] = q[((size_t)(b * L + qi)) * H * D + h * D + t];
    __syncthreads();

    float lm = -FLT_MAX;
    for (int i = t; i < L; i += 256) {
        const float* krow = k + ((size_t)(b * L + i)) * H * D + h * D;
        float acc = 0.f;
        #pragma unroll
        for (int dd = 0; dd < D; ++dd) acc += qs[dd] * krow[dd];
        acc *= 0.125f;
        sc[i] = acc;
        lm = fmaxf(lm, acc);
    }
    #pragma unroll
    for (int off = 32; off >= 1; off >>= 1) lm = fmaxf(lm, __shfl_xor(lm, off));
    if ((t & 63) == 0) red[t >> 6] = lm;
    __syncthreads();
    float gm = fmaxf(fmaxf(red[0], red[1]), fmaxf(red[2], red[3]));

    float ls = 0.f;
    for (int i = t; i < L; i += 256) {
        float e = expf(sc[i] - gm);
        sc[i] = e;
        ls += e;
    }
    #pragma unroll
    for (int off = 32; off >= 1; off >>= 1) ls += __shfl_xor(ls, off);
    __syncthreads();
    if ((t & 63) == 0) red[t >> 6] = ls;
    __syncthreads();
    float inv = 1.0f / (red[0] + red[1] + red[2] + red[3]);

    int d = t & 63;
    int g = t >> 6;
    float acc = 0.f;
    for (int i = g; i < L; i += 4) {
        acc += sc[i] * v[((size_t)(b * L + i)) * H * D + h * D + d];
    }
    ctx_s[g][d] = acc;
    __syncthreads();
    if (g == 0) {
        float c = (ctx_s[0][d] + ctx_s[1][d] + ctx_s[2][d] + ctx_s[3][d]) * inv;
        out[((size_t)(b * L + qi)) * H * D + h * D + d] = c;
    }
}

// ---------------------------------------------------------------------------
extern "C" void kernel_launch(void* const* d_in, const int* in_sizes, int n_in,
                              void* d_out, int out_size, void* d_ws, size_t ws_size,
                              hipStream_t stream) {
    const float* q = (const float*)d_in[0];
    const float* k = (const float*)d_in[1];
    const float* v = (const float*)d_in[2];
    const int* sidx = (const int*)d_in[3];
    float* out = (float*)d_out;

    int SK = in_sizes[3] / L;  // sample_k (40 for this shape)

    // Workspace layout. The partition/partial-M buffers live inside the sc
    // region (dead before scores_kernel writes sc).
    size_t offM = 0;                                        // B*H*L floats
    size_t offMtop = offM + (size_t)B * H * L * sizeof(float);
    size_t offSc = offMtop + (size_t)B * H * U * sizeof(int);
    offSc = (offSc + 255) & ~(size_t)255;
    size_t scBytes = (size_t)B * H * U * L * sizeof(float);

    // inside sc region:
    size_t offCnt = offSc;                                   // NE*L ints = 64KB
    size_t offPartIdx = offCnt + (size_t)NE * L * sizeof(int);
    size_t offPM = (offPartIdx + (size_t)NE * L * 40 * sizeof(int) + 255) & ~(size_t)255;
    size_t offPS = offPM + (size_t)NE * 64 * L * sizeof(float);
    size_t partStuffEnd = offPS + (size_t)NE * 64 * L * sizeof(float);

    size_t offPartial = offSc + scBytes;
    offPartial = (offPartial + 255) & ~(size_t)255;
    size_t needSc = offPartial;
    size_t needAll = offPartial + (size_t)B * H * U * RCH * 64 * sizeof(float);

    float* M = (float*)((char*)d_ws + offM);
    int* Mtop = (int*)((char*)d_ws + offMtop);
    float* sc = (float*)((char*)d_ws + offSc);
    int* cnt = (int*)((char*)d_ws + offCnt);
    int* part = (int*)((char*)d_ws + offPartIdx);
    float* pM = (float*)((char*)d_ws + offPM);
    float* pS = (float*)((char*)d_ws + offPS);
    float* partial = (float*)((char*)d_ws + offPartial);

    int n4 = (B * L * H * D) / 4;

    bool fastM = (SK == 40) && (ws_size >= needSc) && (partStuffEnd <= offSc + scBytes);
    if (fastM) {
        partition_kernel<40><<<(L + 255) / 256, 256, 0, stream>>>(sidx, cnt, part);
        m_lds_kernel<40><<<NE * 64, 512, 0, stream>>>(q, k, cnt, part, pM, pS);
        combine_copy_kernel<<<2048, 256, 0, stream>>>(pM, pS, M, v, out, n4);
    } else {
        copy_v_kernel<<<2048, 256, 0, stream>>>(v, out, n4);
        compute_M_kernel<<<B * L, 256, 0, stream>>>(q, k, sidx, M, SK);
    }
    topk_wave_kernel<<<B * H, 64, 0, stream>>>(M, Mtop);

    if (ws_size >= needSc) {
        scores_kernel<<<B * H * NCH, 256, 0, stream>>>(q, k, Mtop, sc);
        softmax_kernel<<<B * H * U, 256, 0, stream>>>(sc);
        if (ws_size >= needAll) {
            pv_partial_kernel<<<B * H * (U / UG) * RCH, 256, 0, stream>>>(v, sc, partial);
            pv_reduce_kernel<<<B * H * U * 64 / 256, 256, 0, stream>>>(partial, Mtop, out);
        } else {
            pv_kernel<<<B * H * (U / UG), 256, 0, stream>>>(v, sc, Mtop, out);
        }
    } else {
        attn_kernel_fallback<<<B * H * U, 256, 0, stream>>>(q, k, v, Mtop, out);
    }
}